// Round 13
// baseline (202.424 us; speedup 1.0000x reference)
//
#include <hip/hip_runtime.h>
#include <hip/hip_fp16.h>
#include <cstdint>

// R13 = R12 (197.4 us) + gather VMEM-instruction halving:
//   gather1: 4 lanes/node, float2 (4-half) loads  (12.8M loads vs 25.6M)
//   gather2: 8 lanes/node (fewer threads + reduce steps)
// Structure locked per R8/R9/R10: phase fusion regresses on MI355X.

#define F_IN 128
#define F_HID 16
#define PB 1024           // partition/sort block threads
#define PT 8192           // edges per partition tile
#define NBMAX 512         // max buckets (nodes/256), n <= 131072
#define CAPMAX 16384      // max bucket capacity

// ===========================================================================
// Phase 1: counting-sort partition into 256-node dst buckets.
// Packed edge word: r | (c&255)<<17  (needs n <= 2^17). int4 edge loads.
// ===========================================================================
__global__ __launch_bounds__(PB) void partition_kernel(
    const int* __restrict__ row, const int* __restrict__ col,
    int* __restrict__ cursor,        // [NBMAX], zeroed
    int* __restrict__ ping,          // [NB * capB]
    int capB, int NB, int n_edges) {
    __shared__ int sh_hist[NBMAX];
    __shared__ int sh_scan[NBMAX];
    __shared__ int sh_cur[NBMAX];
    __shared__ int sh_base[NBMAX];
    __shared__ int sh_wsum[16];
    __shared__ int sh_packed[PT];
    __shared__ unsigned short sh_bkt[PT];

    int t = threadIdx.x;
    int lane = t & 63;
    int wv = t >> 6;
    int ntiles = (n_edges + PT - 1) / PT;
    bool vec_ok = ((n_edges & 3) == 0);   // col = row + n_edges 16B-aligned

    for (int tile = blockIdx.x; tile < ntiles; tile += gridDim.x) {
        int tbase = tile * PT;
        int tcnt = min(PT, n_edges - tbase);

        if (t < NBMAX) sh_hist[t] = 0;
        __syncthreads();

        int e0 = tbase + t * 8;
        int pk[8], bb[8];
        if (vec_ok && e0 + 8 <= n_edges) {
            int4 a0 = *(const int4*)(row + e0);
            int4 a1 = *(const int4*)(row + e0 + 4);
            int4 c0 = *(const int4*)(col + e0);
            int4 c1 = *(const int4*)(col + e0 + 4);
            int rr[8] = {a0.x, a0.y, a0.z, a0.w, a1.x, a1.y, a1.z, a1.w};
            int cc[8] = {c0.x, c0.y, c0.z, c0.w, c1.x, c1.y, c1.z, c1.w};
#pragma unroll
            for (int k = 0; k < 8; k++) {
                bb[k] = cc[k] >> 8;
                pk[k] = rr[k] | ((cc[k] & 255) << 17);
                atomicAdd(&sh_hist[bb[k]], 1);
            }
        } else {
#pragma unroll
            for (int k = 0; k < 8; k++) {
                int e = e0 + k;
                bb[k] = -1;
                if (e < n_edges) {
                    int r = row[e];
                    int c = col[e];
                    bb[k] = c >> 8;
                    pk[k] = r | ((c & 255) << 17);
                    atomicAdd(&sh_hist[bb[k]], 1);
                }
            }
        }
        __syncthreads();

        // wave-hierarchical inclusive scan of sh_hist[0..511]
        {
            int v = (t < NBMAX) ? sh_hist[t] : 0;
            int incl = v;
#pragma unroll
            for (int off = 1; off < 64; off <<= 1) {
                int u = __shfl_up(incl, off, 64);
                if (lane >= off) incl += u;
            }
            if (lane == 63) sh_wsum[wv] = incl;
            __syncthreads();
            if (t < 16) {
                int s = sh_wsum[t];
#pragma unroll
                for (int off = 1; off < 16; off <<= 1) {
                    int u = __shfl_up(s, off, 16);
                    if (t >= off) s += u;
                }
                sh_wsum[t] = s;
            }
            __syncthreads();
            int wexcl = (wv > 0) ? sh_wsum[wv - 1] : 0;
            if (t < NBMAX) sh_scan[t] = incl + wexcl;
        }
        __syncthreads();

        if (t < NBMAX) {
            int h = sh_hist[t];
            sh_cur[t] = sh_scan[t] - h;
            sh_base[t] = (h > 0 && t < NB) ? atomicAdd(&cursor[t], h) : 0;
        }
        __syncthreads();

        // LDS reorder scatter
#pragma unroll
        for (int k = 0; k < 8; k++) {
            if (bb[k] >= 0) {
                int p = atomicAdd(&sh_cur[bb[k]], 1);
                sh_packed[p] = pk[k];
                sh_bkt[p] = (unsigned short)bb[k];
            }
        }
        __syncthreads();

        // write runs out bucket-contiguously
#pragma unroll
        for (int k = 0; k < 8; k++) {
            int p = t + k * PB;
            if (p < tcnt) {
                int b = sh_bkt[p];
                int off = p - (sh_scan[b] - sh_hist[b]);
                int gp = sh_base[b] + off;
                if (gp < capB) ping[(size_t)b * capB + gp] = sh_packed[p];
            }
        }
        __syncthreads();
    }
}

// ===========================================================================
// Phase 2: per-bucket counting sort ping -> pong (node-contiguous, r only).
// Two global passes (L2-hot). Emits cnt/rowptr.
// ===========================================================================
__global__ __launch_bounds__(PB) void bucket_sort_kernel(
    const int* __restrict__ cursor, const int* __restrict__ ping,
    int* __restrict__ pong, int* __restrict__ cnt, int* __restrict__ rowptr,
    int capB, int n) {
    __shared__ int hist[256];
    __shared__ int scan_[256];
    __shared__ int cur[256];
    __shared__ int wsum[16];

    int b = blockIdx.x, t = threadIdx.x;
    int lane = t & 63;
    int wv = t >> 6;
    int cb = min(cursor[b], capB);
    const int* src = ping + (size_t)b * capB;
    int* dst = pong + (size_t)b * capB;

    if (t < 256) hist[t] = 0;
    __syncthreads();
    for (int i = t; i < cb; i += PB) {
        atomicAdd(&hist[(src[i] >> 17) & 255], 1);
    }
    __syncthreads();

    // wave-hierarchical inclusive scan of hist[0..255]
    {
        int v = (t < 256) ? hist[t] : 0;
        int incl = v;
#pragma unroll
        for (int off = 1; off < 64; off <<= 1) {
            int u = __shfl_up(incl, off, 64);
            if (lane >= off) incl += u;
        }
        if (lane == 63) wsum[wv] = incl;
        __syncthreads();
        if (t < 16) {
            int s = wsum[t];
#pragma unroll
            for (int off = 1; off < 16; off <<= 1) {
                int u = __shfl_up(s, off, 16);
                if (t >= off) s += u;
            }
            wsum[t] = s;
        }
        __syncthreads();
        int wexcl = (wv > 0) ? wsum[wv - 1] : 0;
        if (t < 256) scan_[t] = incl + wexcl;
    }
    __syncthreads();

    if (t < 256) {
        int excl = scan_[t] - hist[t];
        cur[t] = excl;
        int g = b * 256 + t;
        if (g < n) {
            cnt[g] = hist[t];
            rowptr[g] = b * capB + excl;
        }
    }
    __syncthreads();

    for (int i = t; i < cb; i += PB) {
        int v = src[i];
        int p = atomicAdd(&cur[(v >> 17) & 255], 1);
        dst[p] = v & 131071;
    }
}

// ===========================================================================
// Phase 3: h1p = fp16( (x @ W1) * dinv[node] )
// ===========================================================================
__global__ __launch_bounds__(256) void gemm1_kernel(const float* __restrict__ x,
                                                    const float* __restrict__ W1,
                                                    const int* __restrict__ cnt,
                                                    __half* __restrict__ h1p, int n) {
    __shared__ float sW[F_IN * F_HID];
    int tid = threadIdx.x;
    for (int i = tid; i < F_IN * F_HID; i += 256) sW[i] = W1[i];
    __syncthreads();

    int node = blockIdx.x * 256 + tid;
    if (node >= n) return;

    const float4* xr = (const float4*)(x + (size_t)node * F_IN);
    float acc[F_HID];
#pragma unroll
    for (int j = 0; j < F_HID; j++) acc[j] = 0.0f;

#pragma unroll 4
    for (int k4 = 0; k4 < F_IN / 4; k4++) {
        float4 xv = xr[k4];
        const float* w0 = &sW[(k4 * 4 + 0) * F_HID];
        const float* w1 = &sW[(k4 * 4 + 1) * F_HID];
        const float* w2 = &sW[(k4 * 4 + 2) * F_HID];
        const float* w3 = &sW[(k4 * 4 + 3) * F_HID];
#pragma unroll
        for (int j = 0; j < F_HID; j++) {
            acc[j] += xv.x * w0[j] + xv.y * w1[j] + xv.z * w2[j] + xv.w * w3[j];
        }
    }

    float d = rsqrtf((float)cnt[node] + 1.0f);
    __half2 hv[8];
#pragma unroll
    for (int j = 0; j < 8; j++) {
        hv[j] = __floats2half2_rn(acc[2 * j] * d, acc[2 * j + 1] * d);
    }
    float4* o4 = (float4*)(h1p + (size_t)node * F_HID);
    o4[0] = *(float4*)&hv[0];
    o4[1] = *(float4*)&hv[4];
}

// ===========================================================================
// Phase 4: layer-1 gather, 4 lanes per dst node, float2 (4-half) loads.
// Per edge: 4 lanes x 8B = one 32B line; 12.8M loads total.
// ===========================================================================
__global__ __launch_bounds__(256) void gather1_kernel(const int* __restrict__ rowptr,
                                                      const int* __restrict__ cnt,
                                                      const int* __restrict__ eidx,
                                                      const __half* __restrict__ h1p,
                                                      const float* __restrict__ b1,
                                                      const float* __restrict__ W2,
                                                      float* __restrict__ sp, int n) {
    int g = (blockIdx.x * 256 + threadIdx.x) >> 2;  // dst node
    int l = threadIdx.x & 3;                        // feature-quad index
    if (g >= n) return;
    int start = rowptr[g];
    int end = start + cnt[g];

    float a0 = 0.0f, a1 = 0.0f, a2 = 0.0f, a3 = 0.0f;
    for (int base = start; base < end; base += 4) {
        int rem = end - base;
        int e = base + ((l < rem) ? l : 0);
        int r = eidx[e];
        int m_cnt = (rem >= 4) ? 4 : rem;
        if (m_cnt == 4) {
#pragma unroll
            for (int m = 0; m < 4; m++) {
                int rm = __shfl(r, m, 4);
                float2 raw = *(const float2*)(h1p + (size_t)rm * F_HID + 4 * l);
                __half2* hp = (__half2*)&raw;
                float2 f0 = __half22float2(hp[0]);
                float2 f1 = __half22float2(hp[1]);
                a0 += f0.x; a1 += f0.y; a2 += f1.x; a3 += f1.y;
            }
        } else {
            for (int m = 0; m < m_cnt; m++) {
                int rm = __shfl(r, m, 4);
                float2 raw = *(const float2*)(h1p + (size_t)rm * F_HID + 4 * l);
                __half2* hp = (__half2*)&raw;
                float2 f0 = __half22float2(hp[0]);
                float2 f1 = __half22float2(hp[1]);
                a0 += f0.x; a1 += f0.y; a2 += f1.x; a3 += f1.y;
            }
        }
    }

    float dc = rsqrtf((float)cnt[g] + 1.0f);
    float2 sraw = *(const float2*)(h1p + (size_t)g * F_HID + 4 * l);
    __half2* shp = (__half2*)&sraw;
    float2 s0 = __half22float2(shp[0]);
    float2 s1 = __half22float2(shp[1]);
    float v0 = (a0 + s0.x) * dc + b1[4 * l + 0];
    float v1 = (a1 + s0.y) * dc + b1[4 * l + 1];
    float v2 = (a2 + s1.x) * dc + b1[4 * l + 2];
    float v3 = (a3 + s1.y) * dc + b1[4 * l + 3];
    v0 = fmaxf(v0, 0.0f); v1 = fmaxf(v1, 0.0f);
    v2 = fmaxf(v2, 0.0f); v3 = fmaxf(v3, 0.0f);
    float t = v0 * W2[4 * l + 0] + v1 * W2[4 * l + 1] +
              v2 * W2[4 * l + 2] + v3 * W2[4 * l + 3];
    t += __shfl_xor(t, 1, 4);
    t += __shfl_xor(t, 2, 4);
    if (l == 0) sp[g] = t * dc;          // pre-scale by src norm for layer 2
}

// ===========================================================================
// Phase 5: layer-2 gather + sigmoid (8 lanes per node)
// ===========================================================================
__global__ __launch_bounds__(256) void gather2_kernel(const int* __restrict__ rowptr,
                                                      const int* __restrict__ cnt,
                                                      const int* __restrict__ eidx,
                                                      const float* __restrict__ sp,
                                                      const float* __restrict__ b2,
                                                      float* __restrict__ out, int n) {
    int g = (blockIdx.x * 256 + threadIdx.x) >> 3;
    int lane = threadIdx.x & 7;
    if (g >= n) return;
    int start = rowptr[g];
    int end = start + cnt[g];

    float acc = 0.0f;
    for (int e = start + lane; e < end; e += 8) {
        acc += sp[eidx[e]];
    }
    acc += __shfl_xor(acc, 1, 8);
    acc += __shfl_xor(acc, 2, 8);
    acc += __shfl_xor(acc, 4, 8);
    if (lane == 0) {
        float v = (acc + sp[g]) * rsqrtf((float)cnt[g] + 1.0f) + b2[0];
        out[g] = 1.0f / (1.0f + __expf(-v));
    }
}

// ===========================================================================
// FALLBACK (proven R4): fixed-cap per-node buckets, fp32 h1p
// ===========================================================================
__global__ void bucket_scatter_kernel(const int* __restrict__ row,
                                      const int* __restrict__ col,
                                      int* __restrict__ cnt,
                                      int* __restrict__ eidx,
                                      int cap, int n_edges) {
    int e = blockIdx.x * blockDim.x + threadIdx.x;
    if (e < n_edges) {
        int c = col[e];
        int p = atomicAdd(&cnt[c], 1);
        if (p < cap) eidx[(size_t)c * cap + p] = row[e];
    }
}

__global__ __launch_bounds__(256) void gemm1f_kernel(const float* __restrict__ x,
                                                     const float* __restrict__ W1,
                                                     const int* __restrict__ cnt,
                                                     float* __restrict__ h1p, int n) {
    __shared__ float sW[F_IN * F_HID];
    int tid = threadIdx.x;
    for (int i = tid; i < F_IN * F_HID; i += 256) sW[i] = W1[i];
    __syncthreads();
    int node = blockIdx.x * 256 + tid;
    if (node >= n) return;
    const float4* xr = (const float4*)(x + (size_t)node * F_IN);
    float acc[F_HID];
#pragma unroll
    for (int j = 0; j < F_HID; j++) acc[j] = 0.0f;
#pragma unroll 4
    for (int k4 = 0; k4 < F_IN / 4; k4++) {
        float4 xv = xr[k4];
        const float* w0 = &sW[(k4 * 4 + 0) * F_HID];
        const float* w1 = &sW[(k4 * 4 + 1) * F_HID];
        const float* w2 = &sW[(k4 * 4 + 2) * F_HID];
        const float* w3 = &sW[(k4 * 4 + 3) * F_HID];
#pragma unroll
        for (int j = 0; j < F_HID; j++) {
            acc[j] += xv.x * w0[j] + xv.y * w1[j] + xv.z * w2[j] + xv.w * w3[j];
        }
    }
    float d = rsqrtf((float)cnt[node] + 1.0f);
    float4* outp = (float4*)(h1p + (size_t)node * F_HID);
    outp[0] = make_float4(acc[0] * d, acc[1] * d, acc[2] * d, acc[3] * d);
    outp[1] = make_float4(acc[4] * d, acc[5] * d, acc[6] * d, acc[7] * d);
    outp[2] = make_float4(acc[8] * d, acc[9] * d, acc[10] * d, acc[11] * d);
    outp[3] = make_float4(acc[12] * d, acc[13] * d, acc[14] * d, acc[15] * d);
}

__global__ __launch_bounds__(256) void fb_gather1_kernel(const int* __restrict__ cnt,
                                                         const int* __restrict__ eidx,
                                                         const float* __restrict__ h1p,
                                                         const float* __restrict__ b1,
                                                         const float* __restrict__ W2,
                                                         float* __restrict__ sp,
                                                         int cap, int n) {
    int g = (blockIdx.x * 256 + threadIdx.x) >> 4;
    int lane = threadIdx.x & 15;
    if (g >= n) return;
    int start = g * cap;
    int end = start + min(cnt[g], cap);
    float acc = 0.0f;
    for (int base = start; base < end; base += 16) {
        int e = base + lane;
        int r = (e < end) ? eidx[e] : 0;
        int m_cnt = min(16, end - base);
        for (int m = 0; m < m_cnt; m++) {
            int rm = __shfl(r, m, 16);
            acc += h1p[(size_t)rm * F_HID + lane];
        }
    }
    float dc = rsqrtf((float)cnt[g] + 1.0f);
    float v = (acc + h1p[(size_t)g * F_HID + lane]) * dc + b1[lane];
    v = fmaxf(v, 0.0f);
    float t = v * W2[lane];
    t += __shfl_xor(t, 1, 16);
    t += __shfl_xor(t, 2, 16);
    t += __shfl_xor(t, 4, 16);
    t += __shfl_xor(t, 8, 16);
    if (lane == 0) sp[g] = t * dc;
}

__global__ __launch_bounds__(256) void fb_gather2_kernel(const int* __restrict__ cnt,
                                                         const int* __restrict__ eidx,
                                                         const float* __restrict__ sp,
                                                         const float* __restrict__ b2,
                                                         float* __restrict__ out,
                                                         int cap, int n) {
    int g = (blockIdx.x * 256 + threadIdx.x) >> 4;
    int lane = threadIdx.x & 15;
    if (g >= n) return;
    int start = g * cap;
    int end = start + min(cnt[g], cap);
    float acc = 0.0f;
    for (int e = start + lane; e < end; e += 16) {
        acc += sp[eidx[e]];
    }
    acc += __shfl_xor(acc, 1, 16);
    acc += __shfl_xor(acc, 2, 16);
    acc += __shfl_xor(acc, 4, 16);
    acc += __shfl_xor(acc, 8, 16);
    if (lane == 0) {
        float v = (acc + sp[g]) * rsqrtf((float)cnt[g] + 1.0f) + b2[0];
        out[g] = 1.0f / (1.0f + __expf(-v));
    }
}

extern "C" void kernel_launch(void* const* d_in, const int* in_sizes, int n_in,
                              void* d_out, int out_size, void* d_ws, size_t ws_size,
                              hipStream_t stream) {
    const float* x  = (const float*)d_in[0];
    const int*   ei = (const int*)d_in[1];  // [2, E] flat: row then col
    const float* W1 = (const float*)d_in[2];
    const float* b1 = (const float*)d_in[3];
    const float* W2 = (const float*)d_in[4];
    const float* b2 = (const float*)d_in[5];
    float* out = (float*)d_out;

    const int n = in_sizes[0] / F_IN;      // 100000
    const int n_edges = in_sizes[1] / 2;   // 3200000
    const int* row = ei;
    const int* col = ei + n_edges;

    const size_t S = ((size_t)n + 511) & ~(size_t)511;
    const size_t words = ws_size / 4;

    const int B = 256;
    const int gridE = (n_edges + B - 1) / B;
    const int gridN = (n + B - 1) / B;

    const int NB = (n + 255) >> 8;
    int meanB = (NB > 0) ? (n_edges / NB) : 0;
    int capB = ((meanB + meanB / 8 + 1024) + 15) & ~15;  // mean + 12% + slack
    // Layout (words): cnt[S] | rowptr[S] | sp[S] | h1p(half16)[8S] |
    //                 cursor[NBMAX] | ping[NB*capB] | pong[NB*capB]
    size_t need_new = 11 * S + (size_t)NBMAX + 2 * (size_t)NB * (size_t)capB;

    if (n <= 131072 && NB <= NBMAX && capB <= CAPMAX && words >= need_new) {
        int*    cnt    = (int*)d_ws;
        int*    rowptr = cnt + S;
        float*  sp     = (float*)(rowptr + S);
        __half* h1p    = (__half*)(sp + S);
        int*    cursor = (int*)((float*)(sp + S) + 8 * S);
        int*    ping   = cursor + NBMAX;
        int*    pong   = ping + (size_t)NB * capB;

        hipMemsetAsync(cursor, 0, NBMAX * sizeof(int), stream);
        int ntiles = (n_edges + PT - 1) / PT;
        int pgrid = min(2048, ntiles);
        partition_kernel<<<pgrid, PB, 0, stream>>>(row, col, cursor, ping,
                                                   capB, NB, n_edges);
        bucket_sort_kernel<<<NB, PB, 0, stream>>>(cursor, ping, pong, cnt,
                                                  rowptr, capB, n);
        gemm1_kernel<<<gridN, B, 0, stream>>>(x, W1, cnt, h1p, n);
        int gridG1 = (n * 4 + B - 1) / B;   // 4 lanes per node
        gather1_kernel<<<gridG1, B, 0, stream>>>(rowptr, cnt, pong, h1p, b1, W2,
                                                 sp, n);
        int gridG2 = (n * 8 + B - 1) / B;   // 8 lanes per node
        gather2_kernel<<<gridG2, B, 0, stream>>>(rowptr, cnt, pong, sp, b2, out, n);
    } else {
        // FALLBACK (R4): cnt[S] | sp[S] | h1pf[16S] | eidx[n*cap]
        int*   cnt  = (int*)d_ws;
        float* sp   = (float*)(cnt + S);
        float* h1pf = sp + S;
        int*   eidx = (int*)(h1pf + 16 * S);
        size_t tail_words = (words > 18 * S) ? (words - 18 * S) : 0;
        int cap = (int)min((size_t)96, tail_words / (size_t)(n > 0 ? n : 1));
        const int gridG = (n * 16 + B - 1) / B;

        hipMemsetAsync(cnt, 0, (size_t)n * sizeof(int), stream);
        bucket_scatter_kernel<<<gridE, B, 0, stream>>>(row, col, cnt, eidx, cap, n_edges);
        gemm1f_kernel<<<gridN, B, 0, stream>>>(x, W1, cnt, h1pf, n);
        fb_gather1_kernel<<<gridG, B, 0, stream>>>(cnt, eidx, h1pf, b1, W2, sp, cap, n);
        fb_gather2_kernel<<<gridG, B, 0, stream>>>(cnt, eidx, sp, b2, out, cap, n);
    }
}

// Round 14
// 197.359 us; speedup vs baseline: 1.0257x; 1.0257x over previous
//
#include <hip/hip_runtime.h>
#include <hip/hip_fp16.h>
#include <cstdint>

// FINAL (R12 config, best measured 197.4 us; 15.6x over round-1 baseline).
// Session evidence:
//  - atomic scatter-add -> partition+sort+gather rewrite: 3075 -> 199 us
//  - phase fusion / cooperative mega-kernel all regress (R8/R9/R10)
//  - gather lane width: 8 lanes/node optimal (16: more instrs; 4: less MLP)
//  - fp16 h1p: absmax 0.0039 << 0.0103 threshold

#define F_IN 128
#define F_HID 16
#define PB 1024           // partition/sort block threads
#define PT 8192           // edges per partition tile
#define NBMAX 512         // max buckets (nodes/256), n <= 131072
#define CAPMAX 16384      // max bucket capacity

// ===========================================================================
// Phase 1: counting-sort partition into 256-node dst buckets.
// Packed edge word: r | (c&255)<<17  (needs n <= 2^17). int4 edge loads.
// ===========================================================================
__global__ __launch_bounds__(PB) void partition_kernel(
    const int* __restrict__ row, const int* __restrict__ col,
    int* __restrict__ cursor,        // [NBMAX], zeroed
    int* __restrict__ ping,          // [NB * capB]
    int capB, int NB, int n_edges) {
    __shared__ int sh_hist[NBMAX];
    __shared__ int sh_scan[NBMAX];
    __shared__ int sh_cur[NBMAX];
    __shared__ int sh_base[NBMAX];
    __shared__ int sh_wsum[16];
    __shared__ int sh_packed[PT];
    __shared__ unsigned short sh_bkt[PT];

    int t = threadIdx.x;
    int lane = t & 63;
    int wv = t >> 6;
    int ntiles = (n_edges + PT - 1) / PT;
    bool vec_ok = ((n_edges & 3) == 0);   // col = row + n_edges 16B-aligned

    for (int tile = blockIdx.x; tile < ntiles; tile += gridDim.x) {
        int tbase = tile * PT;
        int tcnt = min(PT, n_edges - tbase);

        if (t < NBMAX) sh_hist[t] = 0;
        __syncthreads();

        int e0 = tbase + t * 8;
        int pk[8], bb[8];
        if (vec_ok && e0 + 8 <= n_edges) {
            int4 a0 = *(const int4*)(row + e0);
            int4 a1 = *(const int4*)(row + e0 + 4);
            int4 c0 = *(const int4*)(col + e0);
            int4 c1 = *(const int4*)(col + e0 + 4);
            int rr[8] = {a0.x, a0.y, a0.z, a0.w, a1.x, a1.y, a1.z, a1.w};
            int cc[8] = {c0.x, c0.y, c0.z, c0.w, c1.x, c1.y, c1.z, c1.w};
#pragma unroll
            for (int k = 0; k < 8; k++) {
                bb[k] = cc[k] >> 8;
                pk[k] = rr[k] | ((cc[k] & 255) << 17);
                atomicAdd(&sh_hist[bb[k]], 1);
            }
        } else {
#pragma unroll
            for (int k = 0; k < 8; k++) {
                int e = e0 + k;
                bb[k] = -1;
                if (e < n_edges) {
                    int r = row[e];
                    int c = col[e];
                    bb[k] = c >> 8;
                    pk[k] = r | ((c & 255) << 17);
                    atomicAdd(&sh_hist[bb[k]], 1);
                }
            }
        }
        __syncthreads();

        // wave-hierarchical inclusive scan of sh_hist[0..511]
        {
            int v = (t < NBMAX) ? sh_hist[t] : 0;
            int incl = v;
#pragma unroll
            for (int off = 1; off < 64; off <<= 1) {
                int u = __shfl_up(incl, off, 64);
                if (lane >= off) incl += u;
            }
            if (lane == 63) sh_wsum[wv] = incl;
            __syncthreads();
            if (t < 16) {
                int s = sh_wsum[t];
#pragma unroll
                for (int off = 1; off < 16; off <<= 1) {
                    int u = __shfl_up(s, off, 16);
                    if (t >= off) s += u;
                }
                sh_wsum[t] = s;
            }
            __syncthreads();
            int wexcl = (wv > 0) ? sh_wsum[wv - 1] : 0;
            if (t < NBMAX) sh_scan[t] = incl + wexcl;
        }
        __syncthreads();

        if (t < NBMAX) {
            int h = sh_hist[t];
            sh_cur[t] = sh_scan[t] - h;
            sh_base[t] = (h > 0 && t < NB) ? atomicAdd(&cursor[t], h) : 0;
        }
        __syncthreads();

        // LDS reorder scatter
#pragma unroll
        for (int k = 0; k < 8; k++) {
            if (bb[k] >= 0) {
                int p = atomicAdd(&sh_cur[bb[k]], 1);
                sh_packed[p] = pk[k];
                sh_bkt[p] = (unsigned short)bb[k];
            }
        }
        __syncthreads();

        // write runs out bucket-contiguously
#pragma unroll
        for (int k = 0; k < 8; k++) {
            int p = t + k * PB;
            if (p < tcnt) {
                int b = sh_bkt[p];
                int off = p - (sh_scan[b] - sh_hist[b]);
                int gp = sh_base[b] + off;
                if (gp < capB) ping[(size_t)b * capB + gp] = sh_packed[p];
            }
        }
        __syncthreads();
    }
}

// ===========================================================================
// Phase 2: per-bucket counting sort ping -> pong (node-contiguous, r only).
// Two global passes (L2-hot). Emits cnt/rowptr.
// ===========================================================================
__global__ __launch_bounds__(PB) void bucket_sort_kernel(
    const int* __restrict__ cursor, const int* __restrict__ ping,
    int* __restrict__ pong, int* __restrict__ cnt, int* __restrict__ rowptr,
    int capB, int n) {
    __shared__ int hist[256];
    __shared__ int scan_[256];
    __shared__ int cur[256];
    __shared__ int wsum[16];

    int b = blockIdx.x, t = threadIdx.x;
    int lane = t & 63;
    int wv = t >> 6;
    int cb = min(cursor[b], capB);
    const int* src = ping + (size_t)b * capB;
    int* dst = pong + (size_t)b * capB;

    if (t < 256) hist[t] = 0;
    __syncthreads();
    for (int i = t; i < cb; i += PB) {
        atomicAdd(&hist[(src[i] >> 17) & 255], 1);
    }
    __syncthreads();

    // wave-hierarchical inclusive scan of hist[0..255]
    {
        int v = (t < 256) ? hist[t] : 0;
        int incl = v;
#pragma unroll
        for (int off = 1; off < 64; off <<= 1) {
            int u = __shfl_up(incl, off, 64);
            if (lane >= off) incl += u;
        }
        if (lane == 63) wsum[wv] = incl;
        __syncthreads();
        if (t < 16) {
            int s = wsum[t];
#pragma unroll
            for (int off = 1; off < 16; off <<= 1) {
                int u = __shfl_up(s, off, 16);
                if (t >= off) s += u;
            }
            wsum[t] = s;
        }
        __syncthreads();
        int wexcl = (wv > 0) ? wsum[wv - 1] : 0;
        if (t < 256) scan_[t] = incl + wexcl;
    }
    __syncthreads();

    if (t < 256) {
        int excl = scan_[t] - hist[t];
        cur[t] = excl;
        int g = b * 256 + t;
        if (g < n) {
            cnt[g] = hist[t];
            rowptr[g] = b * capB + excl;
        }
    }
    __syncthreads();

    for (int i = t; i < cb; i += PB) {
        int v = src[i];
        int p = atomicAdd(&cur[(v >> 17) & 255], 1);
        dst[p] = v & 131071;
    }
}

// ===========================================================================
// Phase 3: h1p = fp16( (x @ W1) * dinv[node] )
// ===========================================================================
__global__ __launch_bounds__(256) void gemm1_kernel(const float* __restrict__ x,
                                                    const float* __restrict__ W1,
                                                    const int* __restrict__ cnt,
                                                    __half* __restrict__ h1p, int n) {
    __shared__ float sW[F_IN * F_HID];
    int tid = threadIdx.x;
    for (int i = tid; i < F_IN * F_HID; i += 256) sW[i] = W1[i];
    __syncthreads();

    int node = blockIdx.x * 256 + tid;
    if (node >= n) return;

    const float4* xr = (const float4*)(x + (size_t)node * F_IN);
    float acc[F_HID];
#pragma unroll
    for (int j = 0; j < F_HID; j++) acc[j] = 0.0f;

#pragma unroll 4
    for (int k4 = 0; k4 < F_IN / 4; k4++) {
        float4 xv = xr[k4];
        const float* w0 = &sW[(k4 * 4 + 0) * F_HID];
        const float* w1 = &sW[(k4 * 4 + 1) * F_HID];
        const float* w2 = &sW[(k4 * 4 + 2) * F_HID];
        const float* w3 = &sW[(k4 * 4 + 3) * F_HID];
#pragma unroll
        for (int j = 0; j < F_HID; j++) {
            acc[j] += xv.x * w0[j] + xv.y * w1[j] + xv.z * w2[j] + xv.w * w3[j];
        }
    }

    float d = rsqrtf((float)cnt[node] + 1.0f);
    __half2 hv[8];
#pragma unroll
    for (int j = 0; j < 8; j++) {
        hv[j] = __floats2half2_rn(acc[2 * j] * d, acc[2 * j + 1] * d);
    }
    float4* o4 = (float4*)(h1p + (size_t)node * F_HID);
    o4[0] = *(float4*)&hv[0];
    o4[1] = *(float4*)&hv[4];
}

// ===========================================================================
// Phase 4: layer-1 gather, 8 lanes per dst node, half2 loads.
// 8 independent loads in flight per window (MLP-optimal; 4 and 16 both worse).
// ===========================================================================
__global__ __launch_bounds__(256) void gather1_kernel(const int* __restrict__ rowptr,
                                                      const int* __restrict__ cnt,
                                                      const int* __restrict__ eidx,
                                                      const __half* __restrict__ h1p,
                                                      const float* __restrict__ b1,
                                                      const float* __restrict__ W2,
                                                      float* __restrict__ sp, int n) {
    int g = (blockIdx.x * 256 + threadIdx.x) >> 3;  // dst node
    int l = threadIdx.x & 7;                        // feature-pair index
    if (g >= n) return;
    int start = rowptr[g];
    int end = start + cnt[g];

    float ax = 0.0f, ay = 0.0f;
    for (int base = start; base < end; base += 8) {
        int rem = end - base;
        int e = base + ((l < rem) ? l : 0);
        int r = eidx[e];
        if (rem >= 8) {
#pragma unroll
            for (int m = 0; m < 8; m++) {
                int rm = __shfl(r, m, 8);
                float2 f = __half22float2(*(const __half2*)(h1p + (size_t)rm * F_HID + 2 * l));
                ax += f.x; ay += f.y;
            }
        } else {
            for (int m = 0; m < rem; m++) {
                int rm = __shfl(r, m, 8);
                float2 f = __half22float2(*(const __half2*)(h1p + (size_t)rm * F_HID + 2 * l));
                ax += f.x; ay += f.y;
            }
        }
    }

    float dc = rsqrtf((float)cnt[g] + 1.0f);
    float2 fs = __half22float2(*(const __half2*)(h1p + (size_t)g * F_HID + 2 * l));
    float v0 = (ax + fs.x) * dc + b1[2 * l];
    float v1 = (ay + fs.y) * dc + b1[2 * l + 1];
    v0 = fmaxf(v0, 0.0f);
    v1 = fmaxf(v1, 0.0f);
    float t = v0 * W2[2 * l] + v1 * W2[2 * l + 1];  // fused [16,1] GEMM
    t += __shfl_xor(t, 1, 8);
    t += __shfl_xor(t, 2, 8);
    t += __shfl_xor(t, 4, 8);
    if (l == 0) sp[g] = t * dc;          // pre-scale by src norm for layer 2
}

// ===========================================================================
// Phase 5: layer-2 gather + sigmoid (16 lanes per node)
// ===========================================================================
__global__ __launch_bounds__(256) void gather2_kernel(const int* __restrict__ rowptr,
                                                      const int* __restrict__ cnt,
                                                      const int* __restrict__ eidx,
                                                      const float* __restrict__ sp,
                                                      const float* __restrict__ b2,
                                                      float* __restrict__ out, int n) {
    int g = (blockIdx.x * 256 + threadIdx.x) >> 4;
    int lane = threadIdx.x & 15;
    if (g >= n) return;
    int start = rowptr[g];
    int end = start + cnt[g];

    float acc = 0.0f;
    for (int e = start + lane; e < end; e += 16) {
        acc += sp[eidx[e]];
    }
    acc += __shfl_xor(acc, 1, 16);
    acc += __shfl_xor(acc, 2, 16);
    acc += __shfl_xor(acc, 4, 16);
    acc += __shfl_xor(acc, 8, 16);
    if (lane == 0) {
        float v = (acc + sp[g]) * rsqrtf((float)cnt[g] + 1.0f) + b2[0];
        out[g] = 1.0f / (1.0f + __expf(-v));
    }
}

// ===========================================================================
// FALLBACK (proven R4): fixed-cap per-node buckets, fp32 h1p
// ===========================================================================
__global__ void bucket_scatter_kernel(const int* __restrict__ row,
                                      const int* __restrict__ col,
                                      int* __restrict__ cnt,
                                      int* __restrict__ eidx,
                                      int cap, int n_edges) {
    int e = blockIdx.x * blockDim.x + threadIdx.x;
    if (e < n_edges) {
        int c = col[e];
        int p = atomicAdd(&cnt[c], 1);
        if (p < cap) eidx[(size_t)c * cap + p] = row[e];
    }
}

__global__ __launch_bounds__(256) void gemm1f_kernel(const float* __restrict__ x,
                                                     const float* __restrict__ W1,
                                                     const int* __restrict__ cnt,
                                                     float* __restrict__ h1p, int n) {
    __shared__ float sW[F_IN * F_HID];
    int tid = threadIdx.x;
    for (int i = tid; i < F_IN * F_HID; i += 256) sW[i] = W1[i];
    __syncthreads();
    int node = blockIdx.x * 256 + tid;
    if (node >= n) return;
    const float4* xr = (const float4*)(x + (size_t)node * F_IN);
    float acc[F_HID];
#pragma unroll
    for (int j = 0; j < F_HID; j++) acc[j] = 0.0f;
#pragma unroll 4
    for (int k4 = 0; k4 < F_IN / 4; k4++) {
        float4 xv = xr[k4];
        const float* w0 = &sW[(k4 * 4 + 0) * F_HID];
        const float* w1 = &sW[(k4 * 4 + 1) * F_HID];
        const float* w2 = &sW[(k4 * 4 + 2) * F_HID];
        const float* w3 = &sW[(k4 * 4 + 3) * F_HID];
#pragma unroll
        for (int j = 0; j < F_HID; j++) {
            acc[j] += xv.x * w0[j] + xv.y * w1[j] + xv.z * w2[j] + xv.w * w3[j];
        }
    }
    float d = rsqrtf((float)cnt[node] + 1.0f);
    float4* outp = (float4*)(h1p + (size_t)node * F_HID);
    outp[0] = make_float4(acc[0] * d, acc[1] * d, acc[2] * d, acc[3] * d);
    outp[1] = make_float4(acc[4] * d, acc[5] * d, acc[6] * d, acc[7] * d);
    outp[2] = make_float4(acc[8] * d, acc[9] * d, acc[10] * d, acc[11] * d);
    outp[3] = make_float4(acc[12] * d, acc[13] * d, acc[14] * d, acc[15] * d);
}

__global__ __launch_bounds__(256) void fb_gather1_kernel(const int* __restrict__ cnt,
                                                         const int* __restrict__ eidx,
                                                         const float* __restrict__ h1p,
                                                         const float* __restrict__ b1,
                                                         const float* __restrict__ W2,
                                                         float* __restrict__ sp,
                                                         int cap, int n) {
    int g = (blockIdx.x * 256 + threadIdx.x) >> 4;
    int lane = threadIdx.x & 15;
    if (g >= n) return;
    int start = g * cap;
    int end = start + min(cnt[g], cap);
    float acc = 0.0f;
    for (int base = start; base < end; base += 16) {
        int e = base + lane;
        int r = (e < end) ? eidx[e] : 0;
        int m_cnt = min(16, end - base);
        for (int m = 0; m < m_cnt; m++) {
            int rm = __shfl(r, m, 16);
            acc += h1p[(size_t)rm * F_HID + lane];
        }
    }
    float dc = rsqrtf((float)cnt[g] + 1.0f);
    float v = (acc + h1p[(size_t)g * F_HID + lane]) * dc + b1[lane];
    v = fmaxf(v, 0.0f);
    float t = v * W2[lane];
    t += __shfl_xor(t, 1, 16);
    t += __shfl_xor(t, 2, 16);
    t += __shfl_xor(t, 4, 16);
    t += __shfl_xor(t, 8, 16);
    if (lane == 0) sp[g] = t * dc;
}

__global__ __launch_bounds__(256) void fb_gather2_kernel(const int* __restrict__ cnt,
                                                         const int* __restrict__ eidx,
                                                         const float* __restrict__ sp,
                                                         const float* __restrict__ b2,
                                                         float* __restrict__ out,
                                                         int cap, int n) {
    int g = (blockIdx.x * 256 + threadIdx.x) >> 4;
    int lane = threadIdx.x & 15;
    if (g >= n) return;
    int start = g * cap;
    int end = start + min(cnt[g], cap);
    float acc = 0.0f;
    for (int e = start + lane; e < end; e += 16) {
        acc += sp[eidx[e]];
    }
    acc += __shfl_xor(acc, 1, 16);
    acc += __shfl_xor(acc, 2, 16);
    acc += __shfl_xor(acc, 4, 16);
    acc += __shfl_xor(acc, 8, 16);
    if (lane == 0) {
        float v = (acc + sp[g]) * rsqrtf((float)cnt[g] + 1.0f) + b2[0];
        out[g] = 1.0f / (1.0f + __expf(-v));
    }
}

extern "C" void kernel_launch(void* const* d_in, const int* in_sizes, int n_in,
                              void* d_out, int out_size, void* d_ws, size_t ws_size,
                              hipStream_t stream) {
    const float* x  = (const float*)d_in[0];
    const int*   ei = (const int*)d_in[1];  // [2, E] flat: row then col
    const float* W1 = (const float*)d_in[2];
    const float* b1 = (const float*)d_in[3];
    const float* W2 = (const float*)d_in[4];
    const float* b2 = (const float*)d_in[5];
    float* out = (float*)d_out;

    const int n = in_sizes[0] / F_IN;      // 100000
    const int n_edges = in_sizes[1] / 2;   // 3200000
    const int* row = ei;
    const int* col = ei + n_edges;

    const size_t S = ((size_t)n + 511) & ~(size_t)511;
    const size_t words = ws_size / 4;

    const int B = 256;
    const int gridE = (n_edges + B - 1) / B;
    const int gridN = (n + B - 1) / B;

    const int NB = (n + 255) >> 8;
    int meanB = (NB > 0) ? (n_edges / NB) : 0;
    int capB = ((meanB + meanB / 8 + 1024) + 15) & ~15;  // mean + 12% + slack
    // Layout (words): cnt[S] | rowptr[S] | sp[S] | h1p(half16)[8S] |
    //                 cursor[NBMAX] | ping[NB*capB] | pong[NB*capB]
    size_t need_new = 11 * S + (size_t)NBMAX + 2 * (size_t)NB * (size_t)capB;

    if (n <= 131072 && NB <= NBMAX && capB <= CAPMAX && words >= need_new) {
        int*    cnt    = (int*)d_ws;
        int*    rowptr = cnt + S;
        float*  sp     = (float*)(rowptr + S);
        __half* h1p    = (__half*)(sp + S);
        int*    cursor = (int*)((float*)(sp + S) + 8 * S);
        int*    ping   = cursor + NBMAX;
        int*    pong   = ping + (size_t)NB * capB;

        hipMemsetAsync(cursor, 0, NBMAX * sizeof(int), stream);
        int ntiles = (n_edges + PT - 1) / PT;
        int pgrid = min(2048, ntiles);
        partition_kernel<<<pgrid, PB, 0, stream>>>(row, col, cursor, ping,
                                                   capB, NB, n_edges);
        bucket_sort_kernel<<<NB, PB, 0, stream>>>(cursor, ping, pong, cnt,
                                                  rowptr, capB, n);
        gemm1_kernel<<<gridN, B, 0, stream>>>(x, W1, cnt, h1p, n);
        int gridG1 = (n * 8 + B - 1) / B;   // 8 lanes per node
        gather1_kernel<<<gridG1, B, 0, stream>>>(rowptr, cnt, pong, h1p, b1, W2,
                                                 sp, n);
        int gridG2 = (n * 16 + B - 1) / B;  // 16 lanes per node
        gather2_kernel<<<gridG2, B, 0, stream>>>(rowptr, cnt, pong, sp, b2, out, n);
    } else {
        // FALLBACK (R4): cnt[S] | sp[S] | h1pf[16S] | eidx[n*cap]
        int*   cnt  = (int*)d_ws;
        float* sp   = (float*)(cnt + S);
        float* h1pf = sp + S;
        int*   eidx = (int*)(h1pf + 16 * S);
        size_t tail_words = (words > 18 * S) ? (words - 18 * S) : 0;
        int cap = (int)min((size_t)96, tail_words / (size_t)(n > 0 ? n : 1));
        const int gridG = (n * 16 + B - 1) / B;

        hipMemsetAsync(cnt, 0, (size_t)n * sizeof(int), stream);
        bucket_scatter_kernel<<<gridE, B, 0, stream>>>(row, col, cnt, eidx, cap, n_edges);
        gemm1f_kernel<<<gridN, B, 0, stream>>>(x, W1, cnt, h1pf, n);
        fb_gather1_kernel<<<gridG, B, 0, stream>>>(cnt, eidx, h1pf, b1, W2, sp, cap, n);
        fb_gather2_kernel<<<gridG, B, 0, stream>>>(cnt, eidx, sp, b2, out, cap, n);
    }
}